// Round 1
// baseline (2136.975 us; speedup 1.0000x reference)
//
#include <hip/hip_runtime.h>
#include <hip/hip_bf16.h>

// PolicyNet restructured:
//   c   = b1 + W1[:, :D] @ hist                  (once, [D])
//   QW1 = Q @ W1[:, D:]^T                        (once, [N,D])
//   S   = A @ Q^T            -> softmax rows -> attn (in-place)
//   fused per (m-tile, j-tile):
//       z = attn @ QW1 (K=128); h = relu(z + c)
//       G = A @ W2     (K=2048)
//       partial[jblk][m] = sum_j h*G + A*b2
//   semantic[m] = sum_jblk partial -> softmax over M -> out

// ---------------- small prep kernels ----------------

__global__ __launch_bounds__(256) void c_kernel(const float* __restrict__ W1,
                                                const float* __restrict__ b1,
                                                const float* __restrict__ hist,
                                                float* __restrict__ c) {
  const int wave = threadIdx.x >> 6, lane = threadIdx.x & 63;
  const int j = blockIdx.x * 4 + wave;            // grid 512 -> j < 2048
  const float* row = W1 + (size_t)j * 4096;
  float s = 0.f;
  #pragma unroll 2
  for (int kq = lane; kq < 512; kq += 64) {
    const float4 w = *(const float4*)&row[kq * 4];
    const float4 h = *(const float4*)&hist[kq * 4];
    s += w.x * h.x + w.y * h.y + w.z * h.z + w.w * h.w;
  }
  #pragma unroll
  for (int mask = 1; mask < 64; mask <<= 1) s += __shfl_xor(s, mask);
  if (lane == 0) c[j] = s + b1[j];
}

// C[m][n] = sum_k A[m*lda+k] * B[n*ldb+k]  (B stored row-major over k: "B^T" GEMM)
template <int BM, int TM>
__global__ __launch_bounds__(256) void gemm_bt(const float* __restrict__ A,
                                               const float* __restrict__ B,
                                               float* __restrict__ C,
                                               int K, int lda, int ldb, int ldc) {
  constexpr int BN = 64, BK = 32;
  constexpr int ASTR = BM + 12, BSTR = BN + 4;
  __shared__ float As[BK][ASTR];
  __shared__ float Bs[BK][BSTR];
  const int tid = threadIdx.x;
  const int tx = tid & 15, ty = tid >> 4;
  const int m0 = ty * TM, n0 = tx * 4;
  const size_t bm = (size_t)blockIdx.x * BM, bn = (size_t)blockIdx.y * BN;
  const float* Ab = A + bm * lda;
  const float* Bb = B + bn * ldb;

  float acc[TM][4];
  #pragma unroll
  for (int i = 0; i < TM; ++i)
    #pragma unroll
    for (int j = 0; j < 4; ++j) acc[i][j] = 0.f;

  for (int kt = 0; kt < K; kt += BK) {
    #pragma unroll
    for (int it = 0; it < BM * BK / 4 / 256; ++it) {
      const int idx = it * 256 + tid;
      const int row = idx >> 3, kq = idx & 7;
      const float4 v = *(const float4*)&Ab[(size_t)row * lda + kt + kq * 4];
      As[kq * 4 + 0][row] = v.x; As[kq * 4 + 1][row] = v.y;
      As[kq * 4 + 2][row] = v.z; As[kq * 4 + 3][row] = v.w;
    }
    #pragma unroll
    for (int it = 0; it < BN * BK / 4 / 256; ++it) {
      const int idx = it * 256 + tid;
      const int row = idx >> 3, kq = idx & 7;
      const float4 v = *(const float4*)&Bb[(size_t)row * ldb + kt + kq * 4];
      Bs[kq * 4 + 0][row] = v.x; Bs[kq * 4 + 1][row] = v.y;
      Bs[kq * 4 + 2][row] = v.z; Bs[kq * 4 + 3][row] = v.w;
    }
    __syncthreads();
    #pragma unroll
    for (int k = 0; k < BK; ++k) {
      float av[TM];
      if constexpr (TM == 8) {
        const float4 a0 = *(const float4*)&As[k][m0];
        const float4 a1 = *(const float4*)&As[k][m0 + 4];
        av[0] = a0.x; av[1] = a0.y; av[2] = a0.z; av[3] = a0.w;
        av[4] = a1.x; av[5] = a1.y; av[6] = a1.z; av[7] = a1.w;
      } else {
        #pragma unroll
        for (int i = 0; i < TM; ++i) av[i] = As[k][m0 + i];
      }
      const float4 b = *(const float4*)&Bs[k][n0];
      const float bv[4] = {b.x, b.y, b.z, b.w};
      #pragma unroll
      for (int i = 0; i < TM; ++i)
        #pragma unroll
        for (int j = 0; j < 4; ++j) acc[i][j] = fmaf(av[i], bv[j], acc[i][j]);
    }
    __syncthreads();
  }
  #pragma unroll
  for (int i = 0; i < TM; ++i) {
    float* crow = C + (bm + m0 + i) * (size_t)ldc + bn + n0;
    #pragma unroll
    for (int j = 0; j < 4; ++j) crow[j] = acc[i][j];
  }
}

__global__ __launch_bounds__(256) void softmax_rows(float* __restrict__ S) {
  const int tid = threadIdx.x;
  const int sub = tid & 7;
  const size_t row = (size_t)blockIdx.x * 32 + (tid >> 3);
  float* p = S + row * 128 + sub * 16;
  float4 v0 = ((const float4*)p)[0], v1 = ((const float4*)p)[1];
  float4 v2 = ((const float4*)p)[2], v3 = ((const float4*)p)[3];
  float mx = fmaxf(fmaxf(fmaxf(v0.x, v0.y), fmaxf(v0.z, v0.w)),
                   fmaxf(fmaxf(v1.x, v1.y), fmaxf(v1.z, v1.w)));
  mx = fmaxf(mx, fmaxf(fmaxf(fmaxf(v2.x, v2.y), fmaxf(v2.z, v2.w)),
                       fmaxf(fmaxf(v3.x, v3.y), fmaxf(v3.z, v3.w))));
  mx = fmaxf(mx, __shfl_xor(mx, 1));
  mx = fmaxf(mx, __shfl_xor(mx, 2));
  mx = fmaxf(mx, __shfl_xor(mx, 4));
  v0.x = __expf(v0.x - mx); v0.y = __expf(v0.y - mx); v0.z = __expf(v0.z - mx); v0.w = __expf(v0.w - mx);
  v1.x = __expf(v1.x - mx); v1.y = __expf(v1.y - mx); v1.z = __expf(v1.z - mx); v1.w = __expf(v1.w - mx);
  v2.x = __expf(v2.x - mx); v2.y = __expf(v2.y - mx); v2.z = __expf(v2.z - mx); v2.w = __expf(v2.w - mx);
  v3.x = __expf(v3.x - mx); v3.y = __expf(v3.y - mx); v3.z = __expf(v3.z - mx); v3.w = __expf(v3.w - mx);
  float sm = v0.x + v0.y + v0.z + v0.w + v1.x + v1.y + v1.z + v1.w +
             v2.x + v2.y + v2.z + v2.w + v3.x + v3.y + v3.z + v3.w;
  sm += __shfl_xor(sm, 1);
  sm += __shfl_xor(sm, 2);
  sm += __shfl_xor(sm, 4);
  const float inv = 1.0f / sm;
  v0.x *= inv; v0.y *= inv; v0.z *= inv; v0.w *= inv;
  v1.x *= inv; v1.y *= inv; v1.z *= inv; v1.w *= inv;
  v2.x *= inv; v2.y *= inv; v2.z *= inv; v2.w *= inv;
  v3.x *= inv; v3.y *= inv; v3.z *= inv; v3.w *= inv;
  ((float4*)p)[0] = v0; ((float4*)p)[1] = v1; ((float4*)p)[2] = v2; ((float4*)p)[3] = v3;
}

// ---------------- the big fused kernel ----------------
// grid (128, 32): m-tile 128, j-tile 64.
__global__ __launch_bounds__(256) void fused_zg(const float* __restrict__ A,
                                                const float* __restrict__ attn,
                                                const float* __restrict__ QW1,
                                                const float* __restrict__ W2,
                                                const float* __restrict__ cvec,
                                                const float* __restrict__ b2,
                                                float* __restrict__ partial) {
  constexpr int BM = 128, BN = 64, BK = 32;
  constexpr int ASTR = BM + 12, BSTR = BN + 4;
  __shared__ float As[BK][ASTR];
  __shared__ float Bs[BK][BSTR];
  const int tid = threadIdx.x;
  const int tx = tid & 15, ty = tid >> 4;
  const int m0 = ty * 8, n0 = tx * 4;
  const size_t bm = (size_t)blockIdx.x * BM, bn = (size_t)blockIdx.y * BN;

  float acc[8][4];
  #pragma unroll
  for (int i = 0; i < 8; ++i)
    #pragma unroll
    for (int j = 0; j < 4; ++j) acc[i][j] = 0.f;

#define STAGE_A(BASE, LDA, KT)                                                  \
  {                                                                             \
    const float* Ab_ = (BASE);                                                  \
    _Pragma("unroll")                                                           \
    for (int it = 0; it < 4; ++it) {                                            \
      const int idx = it * 256 + tid;                                           \
      const int row = idx >> 3, kq = idx & 7;                                   \
      const float4 v = *(const float4*)&Ab_[(size_t)row * (LDA) + (KT) + kq * 4]; \
      As[kq * 4 + 0][row] = v.x; As[kq * 4 + 1][row] = v.y;                     \
      As[kq * 4 + 2][row] = v.z; As[kq * 4 + 3][row] = v.w;                     \
    }                                                                           \
  }
#define STAGE_B_NT(BASE, KT)                                                    \
  {                                                                             \
    const float* Bb_ = (BASE) + (size_t)(KT) * 2048 + bn;                       \
    _Pragma("unroll")                                                           \
    for (int it = 0; it < 2; ++it) {                                            \
      const int idx = it * 256 + tid;                                           \
      const int krow = idx >> 4, nq = idx & 15;                                 \
      *(float4*)&Bs[krow][nq * 4] = *(const float4*)&Bb_[(size_t)krow * 2048 + nq * 4]; \
    }                                                                           \
  }
#define INNER()                                                                 \
  _Pragma("unroll")                                                             \
  for (int k = 0; k < BK; ++k) {                                                \
    const float4 a0 = *(const float4*)&As[k][m0];                               \
    const float4 a1 = *(const float4*)&As[k][m0 + 4];                           \
    const float4 b = *(const float4*)&Bs[k][n0];                                \
    const float av[8] = {a0.x, a0.y, a0.z, a0.w, a1.x, a1.y, a1.z, a1.w};       \
    const float bv[4] = {b.x, b.y, b.z, b.w};                                   \
    _Pragma("unroll")                                                           \
    for (int i = 0; i < 8; ++i)                                                 \
      _Pragma("unroll")                                                         \
      for (int j = 0; j < 4; ++j) acc[i][j] = fmaf(av[i], bv[j], acc[i][j]);    \
  }

  // ---- z = attn @ QW1, K = 128 ----
  const float* attn_b = attn + bm * 128;
  for (int kt = 0; kt < 128; kt += BK) {
    STAGE_A(attn_b, 128, kt);
    STAGE_B_NT(QW1, kt);
    __syncthreads();
    INNER();
    __syncthreads();
  }

  // h = relu(z + c)
  float h[8][4];
  {
    const float4 cv = *(const float4*)&cvec[bn + n0];
    const float cc[4] = {cv.x, cv.y, cv.z, cv.w};
    #pragma unroll
    for (int i = 0; i < 8; ++i)
      #pragma unroll
      for (int j = 0; j < 4; ++j) {
        h[i][j] = fmaxf(acc[i][j] + cc[j], 0.f);
        acc[i][j] = 0.f;
      }
  }

  // ---- G = A @ W2, K = 2048 ----
  const float* A_b = A + bm * 2048;
  for (int kt = 0; kt < 2048; kt += BK) {
    STAGE_A(A_b, 2048, kt);
    STAGE_B_NT(W2, kt);
    __syncthreads();
    INNER();
    __syncthreads();
  }

  // epilogue: partial[jblk][m] = sum_j h*G + A*b2  (reduced over the 16 tx lanes)
  const float4 bb = *(const float4*)&b2[bn + n0];
  const float b2v[4] = {bb.x, bb.y, bb.z, bb.w};
  float part[8];
  #pragma unroll
  for (int i = 0; i < 8; ++i) {
    const float4 a4 = *(const float4*)&A[(bm + m0 + i) * 2048 + bn + n0];
    const float aa[4] = {a4.x, a4.y, a4.z, a4.w};
    float s = 0.f;
    #pragma unroll
    for (int j = 0; j < 4; ++j) s += h[i][j] * acc[i][j] + aa[j] * b2v[j];
    part[i] = s;
  }
  #pragma unroll
  for (int i = 0; i < 8; ++i) {
    part[i] += __shfl_xor(part[i], 1);
    part[i] += __shfl_xor(part[i], 2);
    part[i] += __shfl_xor(part[i], 4);
    part[i] += __shfl_xor(part[i], 8);
  }
  if (tx == 0) {
    #pragma unroll
    for (int i = 0; i < 8; ++i)
      partial[(size_t)blockIdx.y * 16384 + bm + m0 + i] = part[i];
  }
#undef STAGE_A
#undef STAGE_B_NT
#undef INNER
}

// ---------------- final reduction + softmax over M ----------------

__global__ __launch_bounds__(256) void k_sem(const float* __restrict__ partial,
                                             float* __restrict__ semantic,
                                             float* __restrict__ bstats) {
  const int m = blockIdx.x * 256 + threadIdx.x;
  float s = 0.f;
  #pragma unroll
  for (int nb = 0; nb < 32; ++nb) s += partial[(size_t)nb * 16384 + m];
  semantic[m] = s;
  float mx = s;
  #pragma unroll
  for (int mask = 1; mask < 64; mask <<= 1) mx = fmaxf(mx, __shfl_xor(mx, mask));
  __shared__ float wmax[4], wsum[4];
  const int wave = threadIdx.x >> 6, lane = threadIdx.x & 63;
  if (lane == 0) wmax[wave] = mx;
  __syncthreads();
  const float bmax = fmaxf(fmaxf(wmax[0], wmax[1]), fmaxf(wmax[2], wmax[3]));
  float e = expf(s - bmax);
  #pragma unroll
  for (int mask = 1; mask < 64; mask <<= 1) e += __shfl_xor(e, mask);
  if (lane == 0) wsum[wave] = e;
  __syncthreads();
  if (threadIdx.x == 0) {
    bstats[blockIdx.x * 2] = bmax;
    bstats[blockIdx.x * 2 + 1] = wsum[0] + wsum[1] + wsum[2] + wsum[3];
  }
}

__global__ void k_combine(const float* __restrict__ bstats, float* __restrict__ gstats) {
  const int t = threadIdx.x;  // 64 threads
  const float bm = bstats[t * 2], bs = bstats[t * 2 + 1];
  float gm = bm;
  #pragma unroll
  for (int mask = 1; mask < 64; mask <<= 1) gm = fmaxf(gm, __shfl_xor(gm, mask));
  float gs = bs * expf(bm - gm);
  #pragma unroll
  for (int mask = 1; mask < 64; mask <<= 1) gs += __shfl_xor(gs, mask);
  if (t == 0) { gstats[0] = gm; gstats[1] = gs; }
}

__global__ __launch_bounds__(256) void k_out(const float* __restrict__ semantic,
                                             const float* __restrict__ gstats,
                                             float* __restrict__ out) {
  const int m = blockIdx.x * 256 + threadIdx.x;
  out[m] = expf(semantic[m] - gstats[0]) / gstats[1];
}

// ---------------- launch ----------------

extern "C" void kernel_launch(void* const* d_in, const int* in_sizes, int n_in,
                              void* d_out, int out_size, void* d_ws, size_t ws_size,
                              hipStream_t stream) {
  (void)in_sizes; (void)n_in; (void)out_size; (void)ws_size;
  const float* A    = (const float*)d_in[0];  // [16384][2048]
  const float* Q    = (const float*)d_in[1];  // [128][2048]
  const float* hist = (const float*)d_in[2];  // [2048]
  const float* W1   = (const float*)d_in[3];  // [2048][4096]
  const float* b1   = (const float*)d_in[4];  // [2048]
  const float* W2   = (const float*)d_in[5];  // [2048][2048]
  const float* b2   = (const float*)d_in[6];  // [2048]
  float* out = (float*)d_out;                 // [16384]

  float* ws = (float*)d_ws;
  float* c_vec    = ws;                       // 2048
  float* qw1      = c_vec + 2048;             // 128*2048
  float* S        = qw1 + 128 * 2048;         // 16384*128  (attn in-place)
  float* partial  = S + (size_t)16384 * 128;  // 32*16384
  float* semantic = partial + 32 * 16384;     // 16384
  float* bstats   = semantic + 16384;         // 128
  float* gstats   = bstats + 128;             // 2

  // c = b1 + W1[:, :2048] @ hist
  c_kernel<<<512, 256, 0, stream>>>(W1, b1, hist, c_vec);
  // QW1[n][j] = sum_k Q[n][k] * W1[j][2048+k]
  gemm_bt<32, 2><<<dim3(4, 32), 256, 0, stream>>>(Q, W1 + 2048, qw1,
                                                  2048, 2048, 4096, 2048);
  // S = A @ Q^T
  gemm_bt<128, 8><<<dim3(128, 2), 256, 0, stream>>>(A, Q, S,
                                                    2048, 2048, 2048, 128);
  // attn = softmax rows (in place)
  softmax_rows<<<512, 256, 0, stream>>>(S);
  // fused z/h/G/dot
  fused_zg<<<dim3(128, 32), 256, 0, stream>>>(A, S, qw1, W2, c_vec, b2, partial);
  // semantic + softmax over M
  k_sem<<<64, 256, 0, stream>>>(partial, semantic, bstats);
  k_combine<<<1, 64, 0, stream>>>(bstats, gstats);
  k_out<<<64, 256, 0, stream>>>(semantic, gstats, out);
}

// Round 2
// 695.652 us; speedup vs baseline: 3.0719x; 3.0719x over previous
//
#include <hip/hip_runtime.h>
#include <hip/hip_bf16.h>

// PolicyNet, MFMA split-bf16 version:
//   c    = b1 + W1[:, :D] @ hist                       (fp32, once)
//   QW1  = Q @ W1[:, D:]^T  (fp32 gemm) -> transpose-split -> QW1T_hi/lo [j][n] bf16
//   W2   -> transpose-split -> W2T_hi/lo [j][k] bf16
//   A    -> rowwise split -> A_hi/A_lo bf16, ab2[m] = A[m]·b2
//   S    = A @ Q^T (fp32 gemm) -> softmax rows -> attn_hi/lo bf16
//   fused (MFMA, 3-product split):
//       z = attn @ QW1T  (K=128);  h = relu(z + c)  [fp32 regs]
//       G = A @ W2T      (K=2048)
//       partial = sum_j h*G        (col-reduce in-wave)
//   semantic[m] = sum partial + ab2[m] -> softmax over M -> out

typedef unsigned short ushort_t;
typedef __attribute__((ext_vector_type(8))) short short8;
typedef __attribute__((ext_vector_type(4))) float f32x4;

#define GLL(gp, lp)                                                              \
  __builtin_amdgcn_global_load_lds(                                              \
      (const __attribute__((address_space(1))) void*)(gp),                       \
      (__attribute__((address_space(3))) void*)(lp), 16, 0, 0)

__device__ __forceinline__ void split_bf16(float x, ushort_t& hi, ushort_t& lo) {
  unsigned u = __float_as_uint(x);
  unsigned r = u + 0x7fffu + ((u >> 16) & 1u);
  hi = (ushort_t)(r >> 16);
  float fh = __uint_as_float(r & 0xffff0000u);
  float xl = x - fh;
  unsigned ul = __float_as_uint(xl);
  unsigned rl = ul + 0x7fffu + ((ul >> 16) & 1u);
  lo = (ushort_t)(rl >> 16);
}

// ---------------- prep kernels ----------------

__global__ __launch_bounds__(256) void c_kernel(const float* __restrict__ W1,
                                                const float* __restrict__ b1,
                                                const float* __restrict__ hist,
                                                float* __restrict__ c) {
  const int wave = threadIdx.x >> 6, lane = threadIdx.x & 63;
  const int j = blockIdx.x * 4 + wave;
  const float* row = W1 + (size_t)j * 4096;
  float s = 0.f;
  #pragma unroll 2
  for (int kq = lane; kq < 512; kq += 64) {
    const float4 w = *(const float4*)&row[kq * 4];
    const float4 h = *(const float4*)&hist[kq * 4];
    s += w.x * h.x + w.y * h.y + w.z * h.z + w.w * h.w;
  }
  #pragma unroll
  for (int mask = 1; mask < 64; mask <<= 1) s += __shfl_xor(s, mask);
  if (lane == 0) c[j] = s + b1[j];
}

// rowwise split of A + ab2[m] = A[m]·b2.  grid 4096 x 256 (wave per row)
__global__ __launch_bounds__(256) void prep_A(const float* __restrict__ A,
                                              const float* __restrict__ b2,
                                              ushort_t* __restrict__ Ahi,
                                              ushort_t* __restrict__ Alo,
                                              float* __restrict__ ab2) {
  const int wv = threadIdx.x >> 6, lane = threadIdx.x & 63;
  const size_t row = (size_t)blockIdx.x * 4 + wv;
  const float* ar = A + row * 2048;
  float dot = 0.f;
  #pragma unroll 2
  for (int c0 = 0; c0 < 2048; c0 += 256) {
    const int col = c0 + lane * 4;
    const float4 v = *(const float4*)&ar[col];
    const float4 bb = *(const float4*)&b2[col];
    dot += v.x * bb.x + v.y * bb.y + v.z * bb.z + v.w * bb.w;
    ushort4 h, l;
    split_bf16(v.x, h.x, l.x); split_bf16(v.y, h.y, l.y);
    split_bf16(v.z, h.z, l.z); split_bf16(v.w, h.w, l.w);
    *(ushort4*)&Ahi[row * 2048 + col] = h;
    *(ushort4*)&Alo[row * 2048 + col] = l;
  }
  #pragma unroll
  for (int mask = 1; mask < 64; mask <<= 1) dot += __shfl_xor(dot, mask);
  if (lane == 0) ab2[row] = dot;
}

// dst_hi/lo[c*ldR + r] = split(src[r*C + c]).  grid (C/64, R/64)
__global__ __launch_bounds__(256) void transpose_split(const float* __restrict__ src,
                                                       int R, int C,
                                                       ushort_t* __restrict__ dhi,
                                                       ushort_t* __restrict__ dlo) {
  __shared__ float T[64][65];
  const int c0 = blockIdx.x * 64, r0 = blockIdx.y * 64;
  const int t = threadIdx.x;
  {
    const int rl = t >> 4, cl = (t & 15) * 4;
    #pragma unroll
    for (int ii = 0; ii < 4; ++ii) {
      const float4 v = *(const float4*)&src[(size_t)(r0 + rl + ii * 16) * C + c0 + cl];
      T[rl + ii * 16][cl + 0] = v.x; T[rl + ii * 16][cl + 1] = v.y;
      T[rl + ii * 16][cl + 2] = v.z; T[rl + ii * 16][cl + 3] = v.w;
    }
  }
  __syncthreads();
  const int cc = t >> 2, rr0 = (t & 3) * 16;
  union { ushort_t u[16]; ushort4 v[4]; } H, L;
  #pragma unroll
  for (int k = 0; k < 16; ++k) {
    split_bf16(T[rr0 + k][cc], H.u[k], L.u[k]);
  }
  ushort_t* ph = dhi + (size_t)(c0 + cc) * R + r0 + rr0;
  ushort_t* pl = dlo + (size_t)(c0 + cc) * R + r0 + rr0;
  #pragma unroll
  for (int k4 = 0; k4 < 4; ++k4) {
    *(ushort4*)&ph[k4 * 4] = H.v[k4];
    *(ushort4*)&pl[k4 * 4] = L.v[k4];
  }
}

// ---------------- fp32 tiled GEMM (B^T layout) for QW1 and S ----------------
template <int BM, int TM>
__global__ __launch_bounds__(256) void gemm_bt(const float* __restrict__ A,
                                               const float* __restrict__ B,
                                               float* __restrict__ C,
                                               int K, int lda, int ldb, int ldc) {
  constexpr int BN = 64, BK = 32;
  constexpr int ASTR = BM + 12, BSTR = BN + 4;
  __shared__ float As[BK][ASTR];
  __shared__ float Bs[BK][BSTR];
  const int tid = threadIdx.x;
  const int tx = tid & 15, ty = tid >> 4;
  const int m0 = ty * TM, n0 = tx * 4;
  const size_t bm = (size_t)blockIdx.x * BM, bn = (size_t)blockIdx.y * BN;
  const float* Ab = A + bm * lda;
  const float* Bb = B + bn * ldb;

  float acc[TM][4];
  #pragma unroll
  for (int i = 0; i < TM; ++i)
    #pragma unroll
    for (int j = 0; j < 4; ++j) acc[i][j] = 0.f;

  for (int kt = 0; kt < K; kt += BK) {
    #pragma unroll
    for (int it = 0; it < BM * BK / 4 / 256; ++it) {
      const int idx = it * 256 + tid;
      const int row = idx >> 3, kq = idx & 7;
      const float4 v = *(const float4*)&Ab[(size_t)row * lda + kt + kq * 4];
      As[kq * 4 + 0][row] = v.x; As[kq * 4 + 1][row] = v.y;
      As[kq * 4 + 2][row] = v.z; As[kq * 4 + 3][row] = v.w;
    }
    #pragma unroll
    for (int it = 0; it < BN * BK / 4 / 256; ++it) {
      const int idx = it * 256 + tid;
      const int row = idx >> 3, kq = idx & 7;
      const float4 v = *(const float4*)&Bb[(size_t)row * ldb + kt + kq * 4];
      Bs[kq * 4 + 0][row] = v.x; Bs[kq * 4 + 1][row] = v.y;
      Bs[kq * 4 + 2][row] = v.z; Bs[kq * 4 + 3][row] = v.w;
    }
    __syncthreads();
    #pragma unroll
    for (int k = 0; k < BK; ++k) {
      float av[TM];
      if constexpr (TM == 8) {
        const float4 a0 = *(const float4*)&As[k][m0];
        const float4 a1 = *(const float4*)&As[k][m0 + 4];
        av[0] = a0.x; av[1] = a0.y; av[2] = a0.z; av[3] = a0.w;
        av[4] = a1.x; av[5] = a1.y; av[6] = a1.z; av[7] = a1.w;
      } else {
        #pragma unroll
        for (int i = 0; i < TM; ++i) av[i] = As[k][m0 + i];
      }
      const float4 b = *(const float4*)&Bs[k][n0];
      const float bv[4] = {b.x, b.y, b.z, b.w};
      #pragma unroll
      for (int i = 0; i < TM; ++i)
        #pragma unroll
        for (int j = 0; j < 4; ++j) acc[i][j] = fmaf(av[i], bv[j], acc[i][j]);
    }
    __syncthreads();
  }
  #pragma unroll
  for (int i = 0; i < TM; ++i) {
    float* crow = C + (bm + m0 + i) * (size_t)ldc + bn + n0;
    #pragma unroll
    for (int j = 0; j < 4; ++j) crow[j] = acc[i][j];
  }
}

// softmax rows of S [16384][128] -> attn_hi/lo bf16
__global__ __launch_bounds__(256) void softmax_split(const float* __restrict__ S,
                                                     ushort_t* __restrict__ ahi,
                                                     ushort_t* __restrict__ alo) {
  const int tid = threadIdx.x;
  const int sub = tid & 7;
  const size_t row = (size_t)blockIdx.x * 32 + (tid >> 3);
  const float* p = S + row * 128 + sub * 16;
  float4 v0 = ((const float4*)p)[0], v1 = ((const float4*)p)[1];
  float4 v2 = ((const float4*)p)[2], v3 = ((const float4*)p)[3];
  float mx = fmaxf(fmaxf(fmaxf(v0.x, v0.y), fmaxf(v0.z, v0.w)),
                   fmaxf(fmaxf(v1.x, v1.y), fmaxf(v1.z, v1.w)));
  mx = fmaxf(mx, fmaxf(fmaxf(fmaxf(v2.x, v2.y), fmaxf(v2.z, v2.w)),
                       fmaxf(fmaxf(v3.x, v3.y), fmaxf(v3.z, v3.w))));
  mx = fmaxf(mx, __shfl_xor(mx, 1));
  mx = fmaxf(mx, __shfl_xor(mx, 2));
  mx = fmaxf(mx, __shfl_xor(mx, 4));
  v0.x = __expf(v0.x - mx); v0.y = __expf(v0.y - mx); v0.z = __expf(v0.z - mx); v0.w = __expf(v0.w - mx);
  v1.x = __expf(v1.x - mx); v1.y = __expf(v1.y - mx); v1.z = __expf(v1.z - mx); v1.w = __expf(v1.w - mx);
  v2.x = __expf(v2.x - mx); v2.y = __expf(v2.y - mx); v2.z = __expf(v2.z - mx); v2.w = __expf(v2.w - mx);
  v3.x = __expf(v3.x - mx); v3.y = __expf(v3.y - mx); v3.z = __expf(v3.z - mx); v3.w = __expf(v3.w - mx);
  float sm = v0.x + v0.y + v0.z + v0.w + v1.x + v1.y + v1.z + v1.w +
             v2.x + v2.y + v2.z + v2.w + v3.x + v3.y + v3.z + v3.w;
  sm += __shfl_xor(sm, 1);
  sm += __shfl_xor(sm, 2);
  sm += __shfl_xor(sm, 4);
  const float inv = 1.0f / sm;
  float vals[16] = {v0.x * inv, v0.y * inv, v0.z * inv, v0.w * inv,
                    v1.x * inv, v1.y * inv, v1.z * inv, v1.w * inv,
                    v2.x * inv, v2.y * inv, v2.z * inv, v2.w * inv,
                    v3.x * inv, v3.y * inv, v3.z * inv, v3.w * inv};
  union { ushort_t u[16]; ushort4 v[4]; } H, L;
  #pragma unroll
  for (int e = 0; e < 16; ++e) split_bf16(vals[e], H.u[e], L.u[e]);
  ushort_t* ph = ahi + row * 128 + sub * 16;
  ushort_t* pl = alo + row * 128 + sub * 16;
  #pragma unroll
  for (int k4 = 0; k4 < 4; ++k4) {
    *(ushort4*)&ph[k4 * 4] = H.v[k4];
    *(ushort4*)&pl[k4 * 4] = L.v[k4];
  }
}

// ---------------- fused MFMA kernel ----------------
// Stages a 128x64 bf16 tile, linear LDS, source pre-swizzled so reads at
// slot = chunk ^ (row&7) are ~2-way conflict-free.
__device__ __forceinline__ void stage4(const ushort_t* g, int ld, short* lbase,
                                       int wv, int lane) {
  const int rl = lane >> 3;       // row within 8-row segment
  const int sw = ((lane & 7) ^ rl) << 3;  // pre-swizzled source chunk offset (elems)
  #pragma unroll
  for (int i = 0; i < 4; ++i) {
    const int seg = wv * 4 + i;
    const int row = seg * 8 + rl;
    const ushort_t* gp = g + (size_t)row * ld + sw;
    GLL(gp, lbase + seg * 512);
  }
}

__global__ __launch_bounds__(256, 2) void fused_zg_mfma(
    const ushort_t* __restrict__ Ahi, const ushort_t* __restrict__ Alo,
    const ushort_t* __restrict__ ANhi, const ushort_t* __restrict__ ANlo,
    const ushort_t* __restrict__ QWhi, const ushort_t* __restrict__ QWlo,
    const ushort_t* __restrict__ W2hi, const ushort_t* __restrict__ W2lo,
    const float* __restrict__ cvec, float* __restrict__ partial) {
  __shared__ short SM[32768];  // 64 KB: 4 tiles of 128x64 bf16
  short* SA_hi = SM;
  short* SA_lo = SM + 8192;
  short* SB_hi = SM + 16384;
  short* SB_lo = SM + 24576;
  const int tid = threadIdx.x, lane = tid & 63, wv = tid >> 6;
  const int wm = (wv >> 1) * 64, wn = (wv & 1) * 64;
  const int frow = lane & 15, kk = lane >> 4;
  const int fr7 = frow & 7;
  const int arow = (wm + frow) * 64;
  const int brow = (wn + frow) * 64;
  const size_t bm = (size_t)blockIdx.x * 128;
  const size_t bn = (size_t)blockIdx.y * 128;

  f32x4 acc[4][4];
  #pragma unroll
  for (int mf = 0; mf < 4; ++mf)
    #pragma unroll
    for (int nf = 0; nf < 4; ++nf) acc[mf][nf] = 0.f;

#define COMPUTE_STEP(ks)                                                        \
  {                                                                             \
    const int sw = (((ks) * 4 + kk) ^ fr7) * 8;                                 \
    short8 ah[4], al[4], bh[4], bl[4];                                          \
    _Pragma("unroll")                                                           \
    for (int mf = 0; mf < 4; ++mf) {                                            \
      ah[mf] = *(const short8*)&SA_hi[arow + mf * 1024 + sw];                   \
      al[mf] = *(const short8*)&SA_lo[arow + mf * 1024 + sw];                   \
    }                                                                           \
    _Pragma("unroll")                                                           \
    for (int nf = 0; nf < 4; ++nf) {                                            \
      bh[nf] = *(const short8*)&SB_hi[brow + nf * 1024 + sw];                   \
      bl[nf] = *(const short8*)&SB_lo[brow + nf * 1024 + sw];                   \
    }                                                                           \
    _Pragma("unroll")                                                           \
    for (int mf = 0; mf < 4; ++mf)                                              \
      _Pragma("unroll")                                                         \
      for (int nf = 0; nf < 4; ++nf) {                                          \
        acc[mf][nf] = __builtin_amdgcn_mfma_f32_16x16x32_bf16(ah[mf], bh[nf], acc[mf][nf], 0, 0, 0); \
        acc[mf][nf] = __builtin_amdgcn_mfma_f32_16x16x32_bf16(ah[mf], bl[nf], acc[mf][nf], 0, 0, 0); \
        acc[mf][nf] = __builtin_amdgcn_mfma_f32_16x16x32_bf16(al[mf], bh[nf], acc[mf][nf], 0, 0, 0); \
      }                                                                         \
  }

  // ---- phase Z: z = attn @ QW1T, K = 128 ----
  for (int kt = 0; kt < 128; kt += 64) {
    stage4(ANhi + bm * 128 + kt, 128, SA_hi, wv, lane);
    stage4(ANlo + bm * 128 + kt, 128, SA_lo, wv, lane);
    stage4(QWhi + bn * 128 + kt, 128, SB_hi, wv, lane);
    stage4(QWlo + bn * 128 + kt, 128, SB_lo, wv, lane);
    asm volatile("s_waitcnt vmcnt(0)" ::: "memory");
    __syncthreads();
    COMPUTE_STEP(0)
    COMPUTE_STEP(1)
    __syncthreads();
  }

  // h = relu(z + c), stays fp32 in registers
  float hreg[4][4][4];
  {
    float ccv[4];
    #pragma unroll
    for (int nf = 0; nf < 4; ++nf) ccv[nf] = cvec[bn + wn + nf * 16 + frow];
    #pragma unroll
    for (int mf = 0; mf < 4; ++mf)
      #pragma unroll
      for (int nf = 0; nf < 4; ++nf)
        #pragma unroll
        for (int r = 0; r < 4; ++r) {
          hreg[mf][nf][r] = fmaxf(acc[mf][nf][r] + ccv[nf], 0.f);
          acc[mf][nf][r] = 0.f;
        }
  }

  // ---- phase G: G = A @ W2T, K = 2048 ----
  for (int kt = 0; kt < 2048; kt += 64) {
    stage4(Ahi + bm * 2048 + kt, 2048, SA_hi, wv, lane);
    stage4(Alo + bm * 2048 + kt, 2048, SA_lo, wv, lane);
    stage4(W2hi + bn * 2048 + kt, 2048, SB_hi, wv, lane);
    stage4(W2lo + bn * 2048 + kt, 2048, SB_lo, wv, lane);
    asm volatile("s_waitcnt vmcnt(0)" ::: "memory");
    __syncthreads();
    COMPUTE_STEP(0)
    COMPUTE_STEP(1)
    __syncthreads();
  }
#undef COMPUTE_STEP

  // epilogue: col-reduce h*G within each 16-lane group
  float part[4][4];
  #pragma unroll
  for (int mf = 0; mf < 4; ++mf)
    #pragma unroll
    for (int r = 0; r < 4; ++r) {
      float s = 0.f;
      #pragma unroll
      for (int nf = 0; nf < 4; ++nf) s += hreg[mf][nf][r] * acc[mf][nf][r];
      part[mf][r] = s;
    }
  #pragma unroll
  for (int mf = 0; mf < 4; ++mf)
    #pragma unroll
    for (int r = 0; r < 4; ++r) {
      part[mf][r] += __shfl_xor(part[mf][r], 1);
      part[mf][r] += __shfl_xor(part[mf][r], 2);
      part[mf][r] += __shfl_xor(part[mf][r], 4);
      part[mf][r] += __shfl_xor(part[mf][r], 8);
    }
  if ((lane & 15) == 0) {
    const size_t slab = (size_t)(blockIdx.y * 2 + (wv & 1)) * 16384;
    #pragma unroll
    for (int mf = 0; mf < 4; ++mf)
      #pragma unroll
      for (int r = 0; r < 4; ++r)
        partial[slab + bm + wm + mf * 16 + kk * 4 + r] = part[mf][r];
  }
}

// ---------------- final reduction + softmax over M ----------------

__global__ __launch_bounds__(256) void k_sem(const float* __restrict__ partial,
                                             const float* __restrict__ ab2,
                                             float* __restrict__ semantic,
                                             float* __restrict__ bstats) {
  const int m = blockIdx.x * 256 + threadIdx.x;
  float s = ab2[m];
  #pragma unroll
  for (int nb = 0; nb < 32; ++nb) s += partial[(size_t)nb * 16384 + m];
  semantic[m] = s;
  float mx = s;
  #pragma unroll
  for (int mask = 1; mask < 64; mask <<= 1) mx = fmaxf(mx, __shfl_xor(mx, mask));
  __shared__ float wmax[4], wsum[4];
  const int wave = threadIdx.x >> 6, lane = threadIdx.x & 63;
  if (lane == 0) wmax[wave] = mx;
  __syncthreads();
  const float bmax = fmaxf(fmaxf(wmax[0], wmax[1]), fmaxf(wmax[2], wmax[3]));
  float e = expf(s - bmax);
  #pragma unroll
  for (int mask = 1; mask < 64; mask <<= 1) e += __shfl_xor(e, mask);
  if (lane == 0) wsum[wave] = e;
  __syncthreads();
  if (threadIdx.x == 0) {
    bstats[blockIdx.x * 2] = bmax;
    bstats[blockIdx.x * 2 + 1] = wsum[0] + wsum[1] + wsum[2] + wsum[3];
  }
}

__global__ void k_combine(const float* __restrict__ bstats, float* __restrict__ gstats) {
  const int t = threadIdx.x;
  const float bm = bstats[t * 2], bs = bstats[t * 2 + 1];
  float gm = bm;
  #pragma unroll
  for (int mask = 1; mask < 64; mask <<= 1) gm = fmaxf(gm, __shfl_xor(gm, mask));
  float gs = bs * expf(bm - gm);
  #pragma unroll
  for (int mask = 1; mask < 64; mask <<= 1) gs += __shfl_xor(gs, mask);
  if (t == 0) { gstats[0] = gm; gstats[1] = gs; }
}

__global__ __launch_bounds__(256) void k_out(const float* __restrict__ semantic,
                                             const float* __restrict__ gstats,
                                             float* __restrict__ out) {
  const int m = blockIdx.x * 256 + threadIdx.x;
  out[m] = expf(semantic[m] - gstats[0]) / gstats[1];
}

// ---------------- launch ----------------

extern "C" void kernel_launch(void* const* d_in, const int* in_sizes, int n_in,
                              void* d_out, int out_size, void* d_ws, size_t ws_size,
                              hipStream_t stream) {
  (void)in_sizes; (void)n_in; (void)out_size; (void)ws_size;
  const float* A    = (const float*)d_in[0];  // [16384][2048]
  const float* Q    = (const float*)d_in[1];  // [128][2048]
  const float* hist = (const float*)d_in[2];  // [2048]
  const float* W1   = (const float*)d_in[3];  // [2048][4096]
  const float* b1   = (const float*)d_in[4];  // [2048]
  const float* W2   = (const float*)d_in[5];  // [2048][2048]
  const float* b2   = (const float*)d_in[6];  // [2048]
  float* out = (float*)d_out;                 // [16384]

  char* ws = (char*)d_ws;
  ushort_t* A_hi   = (ushort_t*)ws;                    ws += (size_t)16384 * 2048 * 2;  // 64 MB
  ushort_t* A_lo   = (ushort_t*)ws;                    ws += (size_t)16384 * 2048 * 2;  // 64 MB
  ushort_t* W2t_hi = (ushort_t*)ws;                    ws += (size_t)2048 * 2048 * 2;   // 8 MB
  ushort_t* W2t_lo = (ushort_t*)ws;                    ws += (size_t)2048 * 2048 * 2;   // 8 MB
  ushort_t* QWt_hi = (ushort_t*)ws;                    ws += (size_t)2048 * 128 * 2;
  ushort_t* QWt_lo = (ushort_t*)ws;                    ws += (size_t)2048 * 128 * 2;
  ushort_t* at_hi  = (ushort_t*)ws;                    ws += (size_t)16384 * 128 * 2;   // 4 MB
  ushort_t* at_lo  = (ushort_t*)ws;                    ws += (size_t)16384 * 128 * 2;   // 4 MB
  float* S         = (float*)ws;                       ws += (size_t)16384 * 128 * 4;   // 8 MB
  float* qw1       = (float*)ws;                       ws += (size_t)128 * 2048 * 4;    // 1 MB
  float* c_vec     = (float*)ws;                       ws += 2048 * 4;
  float* ab2       = (float*)ws;                       ws += 16384 * 4;
  float* partial   = (float*)ws;                       ws += (size_t)32 * 16384 * 4;    // 2 MB
  float* semantic  = (float*)ws;                       ws += 16384 * 4;
  float* bstats    = (float*)ws;                       ws += 128 * 4;
  float* gstats    = (float*)ws;                       ws += 2 * 4;

  // prep
  c_kernel<<<512, 256, 0, stream>>>(W1, b1, hist, c_vec);
  gemm_bt<32, 2><<<dim3(4, 32), 256, 0, stream>>>(Q, W1 + 2048, qw1,
                                                  2048, 2048, 4096, 2048);
  transpose_split<<<dim3(32, 2), 256, 0, stream>>>(qw1, 128, 2048, QWt_hi, QWt_lo);
  transpose_split<<<dim3(32, 32), 256, 0, stream>>>(W2, 2048, 2048, W2t_hi, W2t_lo);
  prep_A<<<4096, 256, 0, stream>>>(A, b2, A_hi, A_lo, ab2);
  // S = A @ Q^T (fp32), softmax -> attn hi/lo
  gemm_bt<128, 8><<<dim3(128, 2), 256, 0, stream>>>(A, Q, S, 2048, 2048, 2048, 128);
  softmax_split<<<512, 256, 0, stream>>>(S, at_hi, at_lo);
  // fused z/h/G/dot (MFMA split-3)
  fused_zg_mfma<<<dim3(128, 16), 256, 0, stream>>>(A_hi, A_lo, at_hi, at_lo,
                                                   QWt_hi, QWt_lo, W2t_hi, W2t_lo,
                                                   c_vec, partial);
  // semantic + softmax over M
  k_sem<<<64, 256, 0, stream>>>(partial, ab2, semantic, bstats);
  k_combine<<<1, 64, 0, stream>>>(bstats, gstats);
  k_out<<<64, 256, 0, stream>>>(semantic, gstats, out);
}